// Round 7
// baseline (143.190 us; speedup 1.0000x reference)
//
#include <hip/hip_runtime.h>

#define T_TOK 64
#define D_OUT 128
#define F_IN 137
#define NCATS 32
#define DC 8
#define K_PAD 160   // accB row stride (bf16 elems)

typedef unsigned short u16;
typedef unsigned int u32;
typedef unsigned char u8;
typedef __attribute__((ext_vector_type(8))) short short8;
typedef __attribute__((ext_vector_type(4))) float f32x4;
typedef __attribute__((ext_vector_type(2))) float f32x2;

__device__ inline u16 bf16rne(float x) {
    unsigned u = __float_as_uint(x);
    return (u16)((u + 0x7FFFu + ((u >> 16) & 1u)) >> 16);
}
__device__ inline unsigned bf16pair(float lo, float hi) {
    unsigned a = __float_as_uint(lo), b = __float_as_uint(hi);
    a = (a + 0x7FFFu + ((a >> 16) & 1u)) >> 16;
    b = (b + 0x7FFFu + ((b >> 16) & 1u)) & 0xFFFF0000u;
    return a | b;
}

// ---- K0: trait table f32 [vocab][128] -> fp8 [vocab][128]; + W prep -------
__global__ __launch_bounds__(256)
void k_cvt8(const float4* __restrict__ src, int4* __restrict__ dst, int n16,
            const float* __restrict__ proj_w, const float* __restrict__ proj_b,
            u16* __restrict__ Wb)
{
    const int i0 = blockIdx.x * 256 + threadIdx.x;
    const int str = gridDim.x * 256;
    for (int k = i0; k < n16; k += str) {
        const float4* sp = src + ((size_t)k << 2);
        float4 f0 = sp[0], f1 = sp[1], f2 = sp[2], f3 = sp[3];
        int4 o;
        unsigned d;
        d = (unsigned)__builtin_amdgcn_cvt_pk_fp8_f32(f0.x, f0.y, 0, false);
        d = (unsigned)__builtin_amdgcn_cvt_pk_fp8_f32(f0.z, f0.w, (int)d, true);
        o.x = (int)d;
        d = (unsigned)__builtin_amdgcn_cvt_pk_fp8_f32(f1.x, f1.y, 0, false);
        d = (unsigned)__builtin_amdgcn_cvt_pk_fp8_f32(f1.z, f1.w, (int)d, true);
        o.y = (int)d;
        d = (unsigned)__builtin_amdgcn_cvt_pk_fp8_f32(f2.x, f2.y, 0, false);
        d = (unsigned)__builtin_amdgcn_cvt_pk_fp8_f32(f2.z, f2.w, (int)d, true);
        o.z = (int)d;
        d = (unsigned)__builtin_amdgcn_cvt_pk_fp8_f32(f3.x, f3.y, 0, false);
        d = (unsigned)__builtin_amdgcn_cvt_pk_fp8_f32(f3.z, f3.w, (int)d, true);
        o.w = (int)d;
        dst[k] = o;
    }
    // fold: W B-fragment prep (first 80 blocks, 20480 elems)
    if (blockIdx.x < 80) {
        int i = blockIdx.x * 256 + threadIdx.x;
        int dt = i / 2560;
        int rem = i - dt * 2560;
        int kc = rem >> 9;
        int rem2 = rem & 511;
        int l = rem2 >> 3, j = rem2 & 7;
        int f = (kc << 5) + ((l >> 4) << 3) + j;
        int d2 = (dt << 4) + (l & 15);
        float v = 0.0f;
        if (f < F_IN) v = proj_w[d2 * F_IN + f];
        else if (f == F_IN) v = proj_b[d2];
        Wb[i] = bf16rne(v);
    }
}

// ---- K1: fp8 gather + weighted accumulate -> accB[N][160] bf16 ------------
// acc row: [0..127] trait, [128..135] cat, [136] ws, [137] sw, [138..159] 0
__global__ __launch_bounds__(256, 8)
void k_gather8(const int* __restrict__ token_ids,
               const float* __restrict__ scores,
               const int* __restrict__ cat_ids,
               const u8* __restrict__ tbl8,
               const float* __restrict__ cat_embed,
               u16* __restrict__ accB,
               float* __restrict__ swf,
               int n_rows)
{
    __shared__ float catE[NCATS * DC];
    __shared__ float wbuf[4][T_TOK];
    __shared__ int   tokbuf[4][T_TOK];
    __shared__ int   catbuf[4][T_TOK];

    const int tid = threadIdx.x;
    if (tid < NCATS * DC) catE[tid] = cat_embed[tid];
    __syncthreads();

    const int wave = tid >> 6;
    const int lane = tid & 63;
    const int p = lane & 7;    // dim block: dims 16p .. 16p+15
    const int g = lane >> 3;   // token group 0..7

    float* wv = wbuf[wave];
    int*   tv = tokbuf[wave];
    int*   cv = catbuf[wave];

    const int nwaves = gridDim.x * 4;
    for (int row = blockIdx.x * 4 + wave; row < n_rows; row += nwaves) {
        const int base = row * T_TOK;
        int   tok = token_ids[base + lane];
        float s   = scores[base + lane];
        int   cat = cat_ids[base + lane];
        float w   = (tok != 0) ? s : 0.0f;
        wv[lane] = w; tv[lane] = tok; cv[lane] = cat;

        float sw = w, ws = w * s;
        #pragma unroll
        for (int off = 32; off >= 1; off >>= 1) {
            sw += __shfl_xor(sw, off);
            ws += __shfl_xor(ws, off);
        }

        float a[16];
        #pragma unroll
        for (int j = 0; j < 16; ++j) a[j] = 0.0f;

        #pragma unroll
        for (int i = 0; i < 8; ++i) {
            int   t  = (i << 3) | g;
            float wt = wv[t];
            int   tk = tv[t];
            const int4 v = *(const int4*)(tbl8 + ((size_t)tk << 7) + (p << 4));
            f32x2 e;
            e = __builtin_amdgcn_cvt_pk_f32_fp8(v.x, false);
            a[0] = fmaf(wt, e.x, a[0]);  a[1] = fmaf(wt, e.y, a[1]);
            e = __builtin_amdgcn_cvt_pk_f32_fp8(v.x, true);
            a[2] = fmaf(wt, e.x, a[2]);  a[3] = fmaf(wt, e.y, a[3]);
            e = __builtin_amdgcn_cvt_pk_f32_fp8(v.y, false);
            a[4] = fmaf(wt, e.x, a[4]);  a[5] = fmaf(wt, e.y, a[5]);
            e = __builtin_amdgcn_cvt_pk_f32_fp8(v.y, true);
            a[6] = fmaf(wt, e.x, a[6]);  a[7] = fmaf(wt, e.y, a[7]);
            e = __builtin_amdgcn_cvt_pk_f32_fp8(v.z, false);
            a[8] = fmaf(wt, e.x, a[8]);  a[9] = fmaf(wt, e.y, a[9]);
            e = __builtin_amdgcn_cvt_pk_f32_fp8(v.z, true);
            a[10] = fmaf(wt, e.x, a[10]); a[11] = fmaf(wt, e.y, a[11]);
            e = __builtin_amdgcn_cvt_pk_f32_fp8(v.w, false);
            a[12] = fmaf(wt, e.x, a[12]); a[13] = fmaf(wt, e.y, a[13]);
            e = __builtin_amdgcn_cvt_pk_f32_fp8(v.w, true);
            a[14] = fmaf(wt, e.x, a[14]); a[15] = fmaf(wt, e.y, a[15]);
        }
        // reduce over token groups (lane bits 3,4,5)
        #pragma unroll
        for (int off = 8; off <= 32; off <<= 1)
            #pragma unroll
            for (int j = 0; j < 16; ++j)
                a[j] += __shfl_xor(a[j], off);

        u16* arow = accB + (size_t)row * K_PAD;
        if (g == 0) {
            int4 o0, o1;
            o0.x = (int)bf16pair(a[0],  a[1]);
            o0.y = (int)bf16pair(a[2],  a[3]);
            o0.z = (int)bf16pair(a[4],  a[5]);
            o0.w = (int)bf16pair(a[6],  a[7]);
            o1.x = (int)bf16pair(a[8],  a[9]);
            o1.y = (int)bf16pair(a[10], a[11]);
            o1.z = (int)bf16pair(a[12], a[13]);
            o1.w = (int)bf16pair(a[14], a[15]);
            int4* dp = (int4*)(arow + (p << 4));
            dp[0] = o0;
            dp[1] = o1;
        }

        // cat part
        {
            int j = lane & 7, g2 = lane >> 3;
            float ca = 0.f;
            #pragma unroll
            for (int t = g2; t < T_TOK; t += 8)
                ca += wv[t] * catE[(cv[t] << 3) + j];
            ca += __shfl_xor(ca, 8);
            ca += __shfl_xor(ca, 16);
            ca += __shfl_xor(ca, 32);
            if (lane < 8) arow[D_OUT + lane] = bf16rne(ca);
        }
        if (lane == 8)  arow[136] = bf16rne(ws);
        if (lane == 9)  arow[137] = bf16rne(sw);
        if (lane == 10) swf[row] = sw;
        if (lane >= 16 && lane < 27)
            *(u32*)(arow + 138 + ((lane - 16) << 1)) = 0u;
    }
}

// ---- K2: MFMA GEMM out = accB[N,160] x Wb[160,128], /sw epilogue ----------
__global__ __launch_bounds__(256)
void k_mfma_proj(const u16* __restrict__ accB,
                 const u16* __restrict__ Wb,
                 const float* __restrict__ swf,
                 float* __restrict__ out,
                 int n_tiles, int n_rows)
{
    const int lane = threadIdx.x & 63;
    const int wid  = (blockIdx.x << 2) + (threadIdx.x >> 6);
    const int nw   = gridDim.x << 2;

    short8 w[8][5];
    #pragma unroll
    for (int dt = 0; dt < 8; ++dt)
        #pragma unroll
        for (int kc = 0; kc < 5; ++kc)
            w[dt][kc] = *(const short8*)(Wb + ((((dt * 5 + kc) << 6) + lane) << 3));

    for (int tile = wid; tile < n_tiles; tile += nw) {
        const int rowbase = tile << 4;
        int row_l = rowbase + (lane & 15);
        if (row_l >= n_rows) row_l = n_rows - 1;
        const u16* ap = accB + (size_t)row_l * K_PAD + ((lane >> 4) << 3);

        short8 a[5];
        #pragma unroll
        for (int kc = 0; kc < 5; ++kc)
            a[kc] = *(const short8*)(ap + (kc << 5));

        f32x4 c[8] = {};
        #pragma unroll
        for (int kc = 0; kc < 5; ++kc)
            #pragma unroll
            for (int dt = 0; dt < 8; ++dt)
                c[dt] = __builtin_amdgcn_mfma_f32_16x16x32_bf16(a[kc], w[dt][kc], c[dt], 0, 0, 0);

        const int r0 = rowbase + ((lane >> 4) << 2);
        float inv[4];
        #pragma unroll
        for (int r = 0; r < 4; ++r) {
            int rr = r0 + r;
            inv[r] = (rr < n_rows) ? 1.0f / fmaxf(swf[rr], 1e-8f) : 0.0f;
        }
        #pragma unroll
        for (int dt = 0; dt < 8; ++dt)
            #pragma unroll
            for (int r = 0; r < 4; ++r) {
                int rr = r0 + r;
                if (rr < n_rows)
                    out[(size_t)rr * D_OUT + (dt << 4) + (lane & 15)] = c[dt][r] * inv[r];
            }
    }
}

// ---------------- fallback (round-1 fused, f32 direct) ---------------------
#define WAVES_PER_BLOCK 16
#define BLOCK_THREADS 1024
__global__ __launch_bounds__(BLOCK_THREADS, 4)
void gwas_fused(const int* __restrict__ token_ids,
                const float* __restrict__ scores,
                const int* __restrict__ cat_ids,
                const float* __restrict__ trait_embed,
                const float* __restrict__ cat_embed,
                const float* __restrict__ proj_w,
                const float* __restrict__ proj_b,
                float* __restrict__ out,
                int n_rows)
{
    __shared__ __align__(16) float Wt[138 * D_OUT];
    __shared__ float catE[NCATS * DC];
    __shared__ __align__(16) float accbuf[WAVES_PER_BLOCK][144];
    __shared__ float wbuf[WAVES_PER_BLOCK][T_TOK];
    __shared__ int   tokbuf[WAVES_PER_BLOCK][T_TOK];
    __shared__ int   catbuf[WAVES_PER_BLOCK][T_TOK];
    const int tid = threadIdx.x;
    for (int e = tid; e < D_OUT * F_IN; e += BLOCK_THREADS) {
        int d = e / F_IN, f = e - d * F_IN;
        Wt[f * D_OUT + d] = proj_w[e];
    }
    if (tid < D_OUT) Wt[137 * D_OUT + tid] = 0.0f;
    if (tid < NCATS * DC) catE[tid] = cat_embed[tid];
    __syncthreads();
    const int wave = tid >> 6, lane = tid & 63, half = lane >> 5, q = lane & 31;
    const float4 b4 = *(const float4*)(proj_b + (q << 2));
    float* accw = accbuf[wave];
    float* wv_ = wbuf[wave]; int* tv_ = tokbuf[wave]; int* cv_ = catbuf[wave];
    for (int row = blockIdx.x * WAVES_PER_BLOCK + wave; row < n_rows;
         row += gridDim.x * WAVES_PER_BLOCK) {
        const int base = row * T_TOK;
        int tok = token_ids[base + lane];
        float s = scores[base + lane];
        int cat = cat_ids[base + lane];
        float w = (tok != 0) ? s : 0.0f;
        wv_[lane] = w; tv_[lane] = tok; cv_[lane] = cat;
        float sw = w, ws = w * s;
        #pragma unroll
        for (int off = 32; off >= 1; off >>= 1) {
            sw += __shfl_xor(sw, off);
            ws += __shfl_xor(ws, off);
        }
        float4 acc = make_float4(0.f, 0.f, 0.f, 0.f);
        #pragma unroll 8
        for (int i = 0; i < 32; ++i) {
            int t = (i << 1) | half;
            float wt = wv_[t];
            int tk = tv_[t];
            const float4* rp = (const float4*)(trait_embed + ((size_t)tk << 7));
            float4 v = rp[q];
            acc.x = fmaf(wt, v.x, acc.x);
            acc.y = fmaf(wt, v.y, acc.y);
            acc.z = fmaf(wt, v.z, acc.z);
            acc.w = fmaf(wt, v.w, acc.w);
        }
        acc.x += __shfl_xor(acc.x, 32);
        acc.y += __shfl_xor(acc.y, 32);
        acc.z += __shfl_xor(acc.z, 32);
        acc.w += __shfl_xor(acc.w, 32);
        if (half == 0) *(float4*)(accw + (q << 2)) = acc;
        {
            int j = lane & 7, g = lane >> 3;
            float ca = 0.f;
            #pragma unroll
            for (int t = g; t < T_TOK; t += 8)
                ca += wv_[t] * catE[(cv_[t] << 3) + j];
            ca += __shfl_xor(ca, 8);
            ca += __shfl_xor(ca, 16);
            ca += __shfl_xor(ca, 32);
            if (lane < 8) accw[D_OUT + lane] = ca;
        }
        if (lane == 8) accw[136] = ws;
        if (lane == 9) accw[137] = 0.f;
        float4 o = make_float4(0.f, 0.f, 0.f, 0.f);
        #pragma unroll 4
        for (int i = 0; i < 69; ++i) {
            float2 a2 = *(const float2*)(accw + (i << 1));
            float a = half ? a2.y : a2.x;
            int f = (i << 1) | half;
            float4 wv = *(const float4*)(Wt + f * D_OUT + (q << 2));
            o.x = fmaf(a, wv.x, o.x);
            o.y = fmaf(a, wv.y, o.y);
            o.z = fmaf(a, wv.z, o.z);
            o.w = fmaf(a, wv.w, o.w);
        }
        o.x += __shfl_xor(o.x, 32);
        o.y += __shfl_xor(o.y, 32);
        o.z += __shfl_xor(o.z, 32);
        o.w += __shfl_xor(o.w, 32);
        if (half == 0) {
            float inv = 1.0f / fmaxf(sw, 1e-8f);
            float4 r;
            r.x = (o.x + b4.x * sw) * inv;
            r.y = (o.y + b4.y * sw) * inv;
            r.z = (o.z + b4.z * sw) * inv;
            r.w = (o.w + b4.w * sw) * inv;
            *(float4*)(out + (size_t)row * D_OUT + (q << 2)) = r;
        }
    }
}

extern "C" void kernel_launch(void* const* d_in, const int* in_sizes, int n_in,
                              void* d_out, int out_size, void* d_ws, size_t ws_size,
                              hipStream_t stream) {
    const int*   token_ids   = (const int*)d_in[0];
    const float* scores      = (const float*)d_in[1];
    const int*   cat_ids     = (const int*)d_in[2];
    const float* trait_embed = (const float*)d_in[3];
    const float* cat_embed   = (const float*)d_in[4];
    const float* proj_w      = (const float*)d_in[5];
    const float* proj_b      = (const float*)d_in[6];
    float*       out         = (float*)d_out;

    const int n_rows = in_sizes[0] / T_TOK;
    const int vocab  = in_sizes[3] / D_OUT;
    const int n_tiles = (n_rows + 15) >> 4;

    size_t tbl_bytes = (size_t)vocab * D_OUT;               // fp8: 1 B/elem
    size_t wb_off    = (tbl_bytes + 255) & ~(size_t)255;
    size_t wb_bytes  = (size_t)8 * 5 * 64 * 8 * sizeof(u16);
    size_t swf_off   = (wb_off + wb_bytes + 255) & ~(size_t)255;
    size_t swf_bytes = (size_t)n_rows * sizeof(float);
    size_t acc_off   = (swf_off + swf_bytes + 255) & ~(size_t)255;
    size_t need      = acc_off + (size_t)n_rows * K_PAD * sizeof(u16);

    if (ws_size >= need) {
        u8*    tbl8 = (u8*)d_ws;
        u16*   Wb   = (u16*)((char*)d_ws + wb_off);
        float* swf  = (float*)((char*)d_ws + swf_off);
        u16*   accB = (u16*)((char*)d_ws + acc_off);

        hipLaunchKernelGGL(k_cvt8, dim3(1024), dim3(256), 0, stream,
                           (const float4*)trait_embed, (int4*)tbl8,
                           (vocab * D_OUT) >> 4, proj_w, proj_b, Wb);
        hipLaunchKernelGGL(k_gather8, dim3(2048), dim3(256), 0, stream,
                           token_ids, scores, cat_ids, tbl8, cat_embed,
                           accB, swf, n_rows);
        hipLaunchKernelGGL(k_mfma_proj, dim3((n_tiles + 3) >> 2), dim3(256), 0, stream,
                           accB, Wb, swf, out, n_tiles, n_rows);
    } else {
        hipLaunchKernelGGL(gwas_fused, dim3(512), dim3(BLOCK_THREADS), 0, stream,
                           token_ids, scores, cat_ids, trait_embed, cat_embed,
                           proj_w, proj_b, out, n_rows);
    }
}

// Round 8
// 54.666 us; speedup vs baseline: 2.6194x; 2.6194x over previous
//
#include <hip/hip_runtime.h>

#define T_TOK 64
#define D_OUT 128
#define F_IN 137
#define NCATS 32
#define DC 8
#define K_PAD 160   // accB row stride (bf16 elems)

typedef unsigned short u16;
typedef unsigned int u32;
typedef unsigned char u8;
typedef __attribute__((ext_vector_type(8))) short short8;
typedef __attribute__((ext_vector_type(4))) float f32x4;
typedef __attribute__((ext_vector_type(2))) float f32x2;

__device__ inline u16 bf16rne(float x) {
    unsigned u = __float_as_uint(x);
    return (u16)((u + 0x7FFFu + ((u >> 16) & 1u)) >> 16);
}
__device__ inline unsigned bf16pair(float lo, float hi) {
    unsigned a = __float_as_uint(lo), b = __float_as_uint(hi);
    a = (a + 0x7FFFu + ((a >> 16) & 1u)) >> 16;
    b = (b + 0x7FFFu + ((b >> 16) & 1u)) & 0xFFFF0000u;
    return a | b;
}

// ---- K0: trait table f32 [vocab][128] -> fp8 [vocab][128]; + W prep -------
__global__ __launch_bounds__(256)
void k_cvt8(const float4* __restrict__ src, int4* __restrict__ dst, int n16,
            const float* __restrict__ proj_w, const float* __restrict__ proj_b,
            u16* __restrict__ Wb)
{
    const int i0 = blockIdx.x * 256 + threadIdx.x;
    const int str = gridDim.x * 256;
    for (int k = i0; k < n16; k += str) {
        const float4* sp = src + ((size_t)k << 2);
        float4 f0 = sp[0], f1 = sp[1], f2 = sp[2], f3 = sp[3];
        int4 o;
        unsigned d;
        d = (unsigned)__builtin_amdgcn_cvt_pk_fp8_f32(f0.x, f0.y, 0, false);
        d = (unsigned)__builtin_amdgcn_cvt_pk_fp8_f32(f0.z, f0.w, (int)d, true);
        o.x = (int)d;
        d = (unsigned)__builtin_amdgcn_cvt_pk_fp8_f32(f1.x, f1.y, 0, false);
        d = (unsigned)__builtin_amdgcn_cvt_pk_fp8_f32(f1.z, f1.w, (int)d, true);
        o.y = (int)d;
        d = (unsigned)__builtin_amdgcn_cvt_pk_fp8_f32(f2.x, f2.y, 0, false);
        d = (unsigned)__builtin_amdgcn_cvt_pk_fp8_f32(f2.z, f2.w, (int)d, true);
        o.z = (int)d;
        d = (unsigned)__builtin_amdgcn_cvt_pk_fp8_f32(f3.x, f3.y, 0, false);
        d = (unsigned)__builtin_amdgcn_cvt_pk_fp8_f32(f3.z, f3.w, (int)d, true);
        o.w = (int)d;
        dst[k] = o;
    }
    // fold: W B-fragment prep (first 80 blocks, 20480 elems)
    if (blockIdx.x < 80) {
        int i = blockIdx.x * 256 + threadIdx.x;
        int dt = i / 2560;
        int rem = i - dt * 2560;
        int kc = rem >> 9;
        int rem2 = rem & 511;
        int l = rem2 >> 3, j = rem2 & 7;
        int f = (kc << 5) + ((l >> 4) << 3) + j;
        int d2 = (dt << 4) + (l & 15);
        float v = 0.0f;
        if (f < F_IN) v = proj_w[d2 * F_IN + f];
        else if (f == F_IN) v = proj_b[d2];
        Wb[i] = bf16rne(v);
    }
}

// ---- K1: fp8 gather, bench-R3 lane layout -> accB[N][160] bf16 ------------
// lane: p = lane&15 owns dims 8p..8p+7 (int2 = 8 fp8); g = lane>>4 = token grp
// acc row: [0..127] trait, [128..135] cat, [136] ws, [137] sw, [138..159] 0
__global__ __launch_bounds__(256, 8)
void k_gather8(const int* __restrict__ token_ids,
               const float* __restrict__ scores,
               const int* __restrict__ cat_ids,
               const u8* __restrict__ tbl8,
               const float* __restrict__ cat_embed,
               u16* __restrict__ accB,
               float* __restrict__ swf,
               int n_rows)
{
    __shared__ float catE[NCATS * DC];
    __shared__ float wbuf[4][T_TOK];
    __shared__ int   tokbuf[4][T_TOK];
    __shared__ int   catbuf[4][T_TOK];

    const int tid = threadIdx.x;
    if (tid < NCATS * DC) catE[tid] = cat_embed[tid];
    __syncthreads();

    const int wave = tid >> 6;
    const int lane = tid & 63;
    const int g = lane >> 4;   // token group 0..3
    const int p = lane & 15;   // dims 8p..8p+7

    float* wv = wbuf[wave];
    int*   tv = tokbuf[wave];
    int*   cv = catbuf[wave];

    const int nwaves = gridDim.x * 4;
    for (int row = blockIdx.x * 4 + wave; row < n_rows; row += nwaves) {
        const int base = row * T_TOK;
        int   tok = token_ids[base + lane];
        float s   = scores[base + lane];
        int   cat = cat_ids[base + lane];
        float w   = (tok != 0) ? s : 0.0f;
        wv[lane] = w; tv[lane] = tok; cv[lane] = cat;

        float sw = w, ws = w * s;
        #pragma unroll
        for (int off = 32; off >= 1; off >>= 1) {
            sw += __shfl_xor(sw, off);
            ws += __shfl_xor(ws, off);
        }

        float a0=0.f,a1=0.f,a2=0.f,a3=0.f,a4=0.f,a5=0.f,a6=0.f,a7=0.f;
        #pragma unroll 4
        for (int i = 0; i < 16; ++i) {
            int   t  = (i << 2) | g;
            float wt = wv[t];
            int   tk = tv[t];
            const int2 v = *(const int2*)(tbl8 + ((size_t)tk << 7) + (p << 3));
            f32x2 e;
            e = __builtin_amdgcn_cvt_pk_f32_fp8(v.x, false);
            a0 = fmaf(wt, e.x, a0);  a1 = fmaf(wt, e.y, a1);
            e = __builtin_amdgcn_cvt_pk_f32_fp8(v.x, true);
            a2 = fmaf(wt, e.x, a2);  a3 = fmaf(wt, e.y, a3);
            e = __builtin_amdgcn_cvt_pk_f32_fp8(v.y, false);
            a4 = fmaf(wt, e.x, a4);  a5 = fmaf(wt, e.y, a5);
            e = __builtin_amdgcn_cvt_pk_f32_fp8(v.y, true);
            a6 = fmaf(wt, e.x, a6);  a7 = fmaf(wt, e.y, a7);
        }
        // reduce across the 4 token-groups (lane bits 4,5)
        a0 += __shfl_xor(a0, 16); a0 += __shfl_xor(a0, 32);
        a1 += __shfl_xor(a1, 16); a1 += __shfl_xor(a1, 32);
        a2 += __shfl_xor(a2, 16); a2 += __shfl_xor(a2, 32);
        a3 += __shfl_xor(a3, 16); a3 += __shfl_xor(a3, 32);
        a4 += __shfl_xor(a4, 16); a4 += __shfl_xor(a4, 32);
        a5 += __shfl_xor(a5, 16); a5 += __shfl_xor(a5, 32);
        a6 += __shfl_xor(a6, 16); a6 += __shfl_xor(a6, 32);
        a7 += __shfl_xor(a7, 16); a7 += __shfl_xor(a7, 32);

        u16* arow = accB + (size_t)row * K_PAD;
        if (lane < 16) {
            int4 v;
            v.x = (int)bf16pair(a0, a1);
            v.y = (int)bf16pair(a2, a3);
            v.z = (int)bf16pair(a4, a5);
            v.w = (int)bf16pair(a6, a7);
            *(int4*)(arow + (p << 3)) = v;
        }

        // cat part
        {
            int j = lane & 7, g2 = lane >> 3;
            float ca = 0.f;
            #pragma unroll
            for (int t = g2; t < T_TOK; t += 8)
                ca += wv[t] * catE[(cv[t] << 3) + j];
            ca += __shfl_xor(ca, 8);
            ca += __shfl_xor(ca, 16);
            ca += __shfl_xor(ca, 32);
            if (lane < 8) arow[D_OUT + lane] = bf16rne(ca);
        }
        if (lane == 8)  arow[136] = bf16rne(ws);
        if (lane == 9)  arow[137] = bf16rne(sw);
        if (lane == 10) swf[row] = sw;
        if (lane >= 16 && lane < 27)
            *(u32*)(arow + 138 + ((lane - 16) << 1)) = 0u;
    }
}

// ---- K2: MFMA GEMM out = accB[N,160] x Wb[160,128], /sw epilogue ----------
__global__ __launch_bounds__(256)
void k_mfma_proj(const u16* __restrict__ accB,
                 const u16* __restrict__ Wb,
                 const float* __restrict__ swf,
                 float* __restrict__ out,
                 int n_tiles, int n_rows)
{
    const int lane = threadIdx.x & 63;
    const int wid  = (blockIdx.x << 2) + (threadIdx.x >> 6);
    const int nw   = gridDim.x << 2;

    short8 w[8][5];
    #pragma unroll
    for (int dt = 0; dt < 8; ++dt)
        #pragma unroll
        for (int kc = 0; kc < 5; ++kc)
            w[dt][kc] = *(const short8*)(Wb + ((((dt * 5 + kc) << 6) + lane) << 3));

    for (int tile = wid; tile < n_tiles; tile += nw) {
        const int rowbase = tile << 4;
        int row_l = rowbase + (lane & 15);
        if (row_l >= n_rows) row_l = n_rows - 1;
        const u16* ap = accB + (size_t)row_l * K_PAD + ((lane >> 4) << 3);

        short8 a[5];
        #pragma unroll
        for (int kc = 0; kc < 5; ++kc)
            a[kc] = *(const short8*)(ap + (kc << 5));

        f32x4 c[8] = {};
        #pragma unroll
        for (int kc = 0; kc < 5; ++kc)
            #pragma unroll
            for (int dt = 0; dt < 8; ++dt)
                c[dt] = __builtin_amdgcn_mfma_f32_16x16x32_bf16(a[kc], w[dt][kc], c[dt], 0, 0, 0);

        const int r0 = rowbase + ((lane >> 4) << 2);
        float inv[4];
        #pragma unroll
        for (int r = 0; r < 4; ++r) {
            int rr = r0 + r;
            inv[r] = (rr < n_rows) ? 1.0f / fmaxf(swf[rr], 1e-8f) : 0.0f;
        }
        #pragma unroll
        for (int dt = 0; dt < 8; ++dt)
            #pragma unroll
            for (int r = 0; r < 4; ++r) {
                int rr = r0 + r;
                if (rr < n_rows)
                    out[(size_t)rr * D_OUT + (dt << 4) + (lane & 15)] = c[dt][r] * inv[r];
            }
    }
}

// ---------------- fallback (round-1 fused, f32 direct) ---------------------
#define WAVES_PER_BLOCK 16
#define BLOCK_THREADS 1024
__global__ __launch_bounds__(BLOCK_THREADS, 4)
void gwas_fused(const int* __restrict__ token_ids,
                const float* __restrict__ scores,
                const int* __restrict__ cat_ids,
                const float* __restrict__ trait_embed,
                const float* __restrict__ cat_embed,
                const float* __restrict__ proj_w,
                const float* __restrict__ proj_b,
                float* __restrict__ out,
                int n_rows)
{
    __shared__ __align__(16) float Wt[138 * D_OUT];
    __shared__ float catE[NCATS * DC];
    __shared__ __align__(16) float accbuf[WAVES_PER_BLOCK][144];
    __shared__ float wbuf[WAVES_PER_BLOCK][T_TOK];
    __shared__ int   tokbuf[WAVES_PER_BLOCK][T_TOK];
    __shared__ int   catbuf[WAVES_PER_BLOCK][T_TOK];
    const int tid = threadIdx.x;
    for (int e = tid; e < D_OUT * F_IN; e += BLOCK_THREADS) {
        int d = e / F_IN, f = e - d * F_IN;
        Wt[f * D_OUT + d] = proj_w[e];
    }
    if (tid < D_OUT) Wt[137 * D_OUT + tid] = 0.0f;
    if (tid < NCATS * DC) catE[tid] = cat_embed[tid];
    __syncthreads();
    const int wave = tid >> 6, lane = tid & 63, half = lane >> 5, q = lane & 31;
    const float4 b4 = *(const float4*)(proj_b + (q << 2));
    float* accw = accbuf[wave];
    float* wv_ = wbuf[wave]; int* tv_ = tokbuf[wave]; int* cv_ = catbuf[wave];
    for (int row = blockIdx.x * WAVES_PER_BLOCK + wave; row < n_rows;
         row += gridDim.x * WAVES_PER_BLOCK) {
        const int base = row * T_TOK;
        int tok = token_ids[base + lane];
        float s = scores[base + lane];
        int cat = cat_ids[base + lane];
        float w = (tok != 0) ? s : 0.0f;
        wv_[lane] = w; tv_[lane] = tok; cv_[lane] = cat;
        float sw = w, ws = w * s;
        #pragma unroll
        for (int off = 32; off >= 1; off >>= 1) {
            sw += __shfl_xor(sw, off);
            ws += __shfl_xor(ws, off);
        }
        float4 acc = make_float4(0.f, 0.f, 0.f, 0.f);
        #pragma unroll 8
        for (int i = 0; i < 32; ++i) {
            int t = (i << 1) | half;
            float wt = wv_[t];
            int tk = tv_[t];
            const float4* rp = (const float4*)(trait_embed + ((size_t)tk << 7));
            float4 v = rp[q];
            acc.x = fmaf(wt, v.x, acc.x);
            acc.y = fmaf(wt, v.y, acc.y);
            acc.z = fmaf(wt, v.z, acc.z);
            acc.w = fmaf(wt, v.w, acc.w);
        }
        acc.x += __shfl_xor(acc.x, 32);
        acc.y += __shfl_xor(acc.y, 32);
        acc.z += __shfl_xor(acc.z, 32);
        acc.w += __shfl_xor(acc.w, 32);
        if (half == 0) *(float4*)(accw + (q << 2)) = acc;
        {
            int j = lane & 7, g = lane >> 3;
            float ca = 0.f;
            #pragma unroll
            for (int t = g; t < T_TOK; t += 8)
                ca += wv_[t] * catE[(cv_[t] << 3) + j];
            ca += __shfl_xor(ca, 8);
            ca += __shfl_xor(ca, 16);
            ca += __shfl_xor(ca, 32);
            if (lane < 8) accw[D_OUT + lane] = ca;
        }
        if (lane == 8) accw[136] = ws;
        if (lane == 9) accw[137] = 0.f;
        float4 o = make_float4(0.f, 0.f, 0.f, 0.f);
        #pragma unroll 4
        for (int i = 0; i < 69; ++i) {
            float2 a2 = *(const float2*)(accw + (i << 1));
            float a = half ? a2.y : a2.x;
            int f = (i << 1) | half;
            float4 wv = *(const float4*)(Wt + f * D_OUT + (q << 2));
            o.x = fmaf(a, wv.x, o.x);
            o.y = fmaf(a, wv.y, o.y);
            o.z = fmaf(a, wv.z, o.z);
            o.w = fmaf(a, wv.w, o.w);
        }
        o.x += __shfl_xor(o.x, 32);
        o.y += __shfl_xor(o.y, 32);
        o.z += __shfl_xor(o.z, 32);
        o.w += __shfl_xor(o.w, 32);
        if (half == 0) {
            float inv = 1.0f / fmaxf(sw, 1e-8f);
            float4 r;
            r.x = (o.x + b4.x * sw) * inv;
            r.y = (o.y + b4.y * sw) * inv;
            r.z = (o.z + b4.z * sw) * inv;
            r.w = (o.w + b4.w * sw) * inv;
            *(float4*)(out + (size_t)row * D_OUT + (q << 2)) = r;
        }
    }
}

extern "C" void kernel_launch(void* const* d_in, const int* in_sizes, int n_in,
                              void* d_out, int out_size, void* d_ws, size_t ws_size,
                              hipStream_t stream) {
    const int*   token_ids   = (const int*)d_in[0];
    const float* scores      = (const float*)d_in[1];
    const int*   cat_ids     = (const int*)d_in[2];
    const float* trait_embed = (const float*)d_in[3];
    const float* cat_embed   = (const float*)d_in[4];
    const float* proj_w      = (const float*)d_in[5];
    const float* proj_b      = (const float*)d_in[6];
    float*       out         = (float*)d_out;

    const int n_rows = in_sizes[0] / T_TOK;
    const int vocab  = in_sizes[3] / D_OUT;
    const int n_tiles = (n_rows + 15) >> 4;

    size_t tbl_bytes = (size_t)vocab * D_OUT;               // fp8: 1 B/elem
    size_t wb_off    = (tbl_bytes + 255) & ~(size_t)255;
    size_t wb_bytes  = (size_t)8 * 5 * 64 * 8 * sizeof(u16);
    size_t swf_off   = (wb_off + wb_bytes + 255) & ~(size_t)255;
    size_t swf_bytes = (size_t)n_rows * sizeof(float);
    size_t acc_off   = (swf_off + swf_bytes + 255) & ~(size_t)255;
    size_t need      = acc_off + (size_t)n_rows * K_PAD * sizeof(u16);

    if (ws_size >= need) {
        u8*    tbl8 = (u8*)d_ws;
        u16*   Wb   = (u16*)((char*)d_ws + wb_off);
        float* swf  = (float*)((char*)d_ws + swf_off);
        u16*   accB = (u16*)((char*)d_ws + acc_off);

        hipLaunchKernelGGL(k_cvt8, dim3(1024), dim3(256), 0, stream,
                           (const float4*)trait_embed, (int4*)tbl8,
                           (vocab * D_OUT) >> 4, proj_w, proj_b, Wb);
        hipLaunchKernelGGL(k_gather8, dim3(2048), dim3(256), 0, stream,
                           token_ids, scores, cat_ids, tbl8, cat_embed,
                           accB, swf, n_rows);
        hipLaunchKernelGGL(k_mfma_proj, dim3((n_tiles + 3) >> 2), dim3(256), 0, stream,
                           accB, Wb, swf, out, n_tiles, n_rows);
    } else {
        hipLaunchKernelGGL(gwas_fused, dim3(512), dim3(BLOCK_THREADS), 0, stream,
                           token_ids, scores, cat_ids, trait_embed, cat_embed,
                           proj_w, proj_b, out, n_rows);
    }
}